// Round 6
// baseline (182.680 us; speedup 1.0000x reference)
//
#include <hip/hip_runtime.h>
#include <math.h>

#define BB 4
#define NN 6
#define DD 41
#define CC 64
#define FHh 16
#define FWw 44
#define NXg 200
#define NYg 200
#define NZg 1
#define NPIX (BB*NN*FHh*FWw)           // 16896
#define NSLOT 128
#define NOVF  (FHh*DD)                 // 656 worst-case points per column
#define OUTFLOATS (BB*NZg*NXg*NYg*CC)  // 10,240,000 floats = 40.96 MB
#define XYg (NXg*NYg)                  // 40000

__device__ __forceinline__ void inv3x3d(const double m[9], double o[9]) {
    double a=m[0],b=m[1],c=m[2],d=m[3],e=m[4],f=m[5],g=m[6],h=m[7],i=m[8];
    double A = e*i - f*h;
    double Bv = -(d*i - f*g);
    double Cv = d*h - e*g;
    double det = a*A + b*Bv + c*Cv;
    double r = 1.0/det;
    o[0]=A*r;  o[1]=-(b*i-c*h)*r; o[2]=(b*f-c*e)*r;
    o[3]=Bv*r; o[4]=(a*i-c*g)*r;  o[5]=-(a*f-c*d)*r;
    o[6]=Cv*r; o[7]=-(a*h-b*g)*r; o[8]=(a*e-b*d)*r;
}

// fast zero-fill: grid-stride float4
__global__ __launch_bounds__(256)
void lss_zero(float4* __restrict__ p, int n4)
{
    const int stride = gridDim.x * 256;
    for (int i = blockIdx.x * 256 + threadIdx.x; i < n4; i += stride)
        p[i] = make_float4(0.f, 0.f, 0.f, 0.f);
}

// One block per (b,n,w) column. Dedup voxels in an LDS hash table (all 16 h
// rows of a column share voxels when geometry collapses them), then emit one
// 64-lane atomic set per unique voxel DIRECTLY into the final
// out[bz][c][x][y] layout (lane = channel, stride XYg between lanes).
__global__ __launch_bounds__(256)
void lss_scatter_fused(const float* __restrict__ xf,
                       const float* __restrict__ rots,
                       const float* __restrict__ trans,
                       const float* __restrict__ intr,
                       const float* __restrict__ prots,
                       const float* __restrict__ ptrans,
                       float* __restrict__ out)
{
    __shared__ float s_lg[FHh * FWw];        // logits [h][d] (row stride 44)
    __shared__ float s_feat[FHh * CC];       // feats  [h][c]
    __shared__ float s_coef[NSLOT * 17];     // per-slot per-h coefficient (pad 17)
    __shared__ int   s_keys[NSLOT];
    __shared__ short s_list[NSLOT];          // compacted occupied-slot list
    __shared__ int   s_nslot;
    __shared__ int2  s_ovf[NOVF];
    __shared__ float s_ovfw[NOVF];
    __shared__ int   s_ovfcnt;

    const int tid  = threadIdx.x;
    const int lane = tid & 63;
    const int wv   = tid >> 6;          // 0..3

    const int bid = blockIdx.x;         // 0..1055
    const int w   = bid % FWw;
    const int rem = bid / FWw;
    const int n   = rem % NN;
    const int b   = rem / NN;
    const int cam = b*NN + n;
    const float* colbase = xf + (size_t)cam * (DD+CC) * FHh * FWw + w;

    // ---- init LDS ----
    if (tid < NSLOT) s_keys[tid] = -1;
    for (int i = tid; i < NSLOT*17; i += 256) s_coef[i] = 0.0f;
    if (tid == 0) { s_nslot = 0; s_ovfcnt = 0; }

    // ---- cooperative stage of the whole column: 1680 scalars ----
    for (int t = tid; t < (DD+CC)*FHh; t += 256) {
        int h  = t / (DD+CC);
        int ch = t - h*(DD+CC);
        float v = colbase[(size_t)ch * (FHh*FWw) + h * FWw];
        if (ch < DD) s_lg[h*FWw + ch] = v;
        else         s_feat[(h << 6) + (ch - DD)] = v;
    }

    // ---- per-camera transform (double precision, redundant per thread) ----
    double K9[9], P9[9], R9[9];
    #pragma unroll
    for (int i = 0; i < 9; ++i) {
        K9[i] = (double)intr [cam*9 + i];
        P9[i] = (double)prots[cam*9 + i];
        R9[i] = (double)rots [cam*9 + i];
    }
    double Kinv[9], Pinv[9];
    inv3x3d(K9, Kinv);
    inv3x3d(P9, Pinv);
    double M[9];
    #pragma unroll
    for (int i = 0; i < 3; ++i)
        #pragma unroll
        for (int j = 0; j < 3; ++j)
            M[i*3+j] = R9[i*3+0]*Kinv[0*3+j] + R9[i*3+1]*Kinv[1*3+j] + R9[i*3+2]*Kinv[2*3+j];
    const double tx  = (double)trans [cam*3+0], ty  = (double)trans [cam*3+1], tz  = (double)trans [cam*3+2];
    const double ptx = (double)ptrans[cam*3+0], pty = (double)ptrans[cam*3+1], ptz = (double)ptrans[cam*3+2];

    __syncthreads();

    // ---- softmax + geometry + hash insert; wave wv handles h = wv*4..wv*4+3
    for (int r = 0; r < 4; ++r) {
        const int h = (wv << 2) + r;
        float logit = (lane < DD) ? s_lg[h*FWw + lane] : -INFINITY;
        float mx = logit;
        #pragma unroll
        for (int off = 32; off; off >>= 1) mx = fmaxf(mx, __shfl_xor(mx, off));
        float ex = (lane < DD) ? expf(logit - mx) : 0.0f;
        float sm = ex;
        #pragma unroll
        for (int off = 32; off; off >>= 1) sm += __shfl_xor(sm, off);
        const float wgt = ex / sm;

        int vox = -1;
        if (lane < DD) {
            double dz = 4.0 + (double)lane;
            double xs = (double)w * (703.0/43.0);
            double ys = (double)h * 17.0;
            double px = xs - ptx, py = ys - pty, pz = dz - ptz;
            double qx = Pinv[0]*px + Pinv[1]*py + Pinv[2]*pz;
            double qy = Pinv[3]*px + Pinv[4]*py + Pinv[5]*pz;
            double qz = Pinv[6]*px + Pinv[7]*py + Pinv[8]*pz;
            qx *= qz; qy *= qz;
            double gx = M[0]*qx + M[1]*qy + M[2]*qz + tx;
            double gy = M[3]*qx + M[4]*qy + M[5]*qz + ty;
            double gz = M[6]*qx + M[7]*qy + M[8]*qz + tz;
            double fx = floor((gx + 50.0) / 0.5);
            double fy = floor((gy + 50.0) / 0.5);
            double fz = floor((gz + 10.0) / 20.0);
            if (fx >= 0.0 && fx < (double)NXg &&
                fy >= 0.0 && fy < (double)NYg &&
                fz >= 0.0 && fz < (double)NZg) {
                int ix = (int)fx, iy = (int)fy, iz = (int)fz;
                vox = ((b*NZg + iz)*NXg + ix)*NYg + iy;   // < 160000
            }
        }

        if (vox >= 0) {
            unsigned slot = (((unsigned)vox * 2654435761u) >> 18) & (NSLOT-1);
            bool done = false;
            for (int probe = 0; probe < NSLOT; ++probe) {
                int prev = atomicCAS(&s_keys[slot], -1, vox);
                if (prev == -1) {
                    int k = atomicAdd(&s_nslot, 1);
                    s_list[k] = (short)slot;
                }
                if (prev == -1 || prev == vox) {
                    atomicAdd(&s_coef[slot*17 + h], wgt);
                    done = true;
                    break;
                }
                slot = (slot + 1) & (NSLOT-1);
            }
            if (!done) {   // table full: spill (generic-correctness fallback)
                int k = atomicAdd(&s_ovfcnt, 1);
                s_ovf[k]  = make_int2(vox, h);
                s_ovfw[k] = wgt;
            }
        }
    }

    __syncthreads();

    // ---- emit: one 64-lane atomic set per unique voxel, final layout ----
    const int nocc = s_nslot;
    for (int e = wv; e < nocc; e += 4) {
        int slot = s_list[e];
        int vox  = s_keys[slot];
        int bz   = vox / XYg;
        int xy   = vox - bz * XYg;
        float acc = 0.0f;
        #pragma unroll
        for (int h = 0; h < FHh; ++h)
            acc += s_coef[slot*17 + h] * s_feat[(h << 6) + lane];
        atomicAdd(&out[(size_t)bz * (CC*XYg) + (size_t)lane * XYg + xy], acc);
    }
    // ---- overflow entries (rare, generic fallback) ----
    const int novf = s_ovfcnt;
    for (int e = wv; e < novf; e += 4) {
        int vox = s_ovf[e].x, h = s_ovf[e].y;
        int bz  = vox / XYg;
        int xy  = vox - bz * XYg;
        atomicAdd(&out[(size_t)bz * (CC*XYg) + (size_t)lane * XYg + xy],
                  s_ovfw[e] * s_feat[(h << 6) + lane]);
    }
}

extern "C" void kernel_launch(void* const* d_in, const int* in_sizes, int n_in,
                              void* d_out, int out_size, void* d_ws, size_t ws_size,
                              hipStream_t stream) {
    const float* xf     = (const float*)d_in[0];
    const float* rots   = (const float*)d_in[1];
    const float* trans  = (const float*)d_in[2];
    const float* intr   = (const float*)d_in[3];
    const float* prots  = (const float*)d_in[4];
    const float* ptrans = (const float*)d_in[5];
    float* out = (float*)d_out;

    lss_zero<<<dim3(2048), dim3(256), 0, stream>>>((float4*)out, OUTFLOATS/4);
    lss_scatter_fused<<<dim3(BB*NN*FWw), dim3(256), 0, stream>>>(
        xf, rots, trans, intr, prots, ptrans, out);
}

// Round 7
// 56.800 us; speedup vs baseline: 3.2162x; 3.2162x over previous
//
#include <hip/hip_runtime.h>
#include <math.h>

#define BB 4
#define NN 6
#define DD 41
#define CC 64
#define FHh 16
#define FWw 44
#define NXg 200
#define NYg 200
#define NZg 1
#define NSLOT 128
#define NOVF  (FHh*DD)                 // 656 worst-case points per column
#define WSFLOATS (BB*NZg*NXg*NYg*CC)   // 10,240,000 floats = 40.96 MB
#define XYg (NXg*NYg)                  // 40000
#define NCOL (BB*NN*FWw)               // 1056 columns

__device__ __forceinline__ void inv3x3d(const double m[9], double o[9]) {
    double a=m[0],b=m[1],c=m[2],d=m[3],e=m[4],f=m[5],g=m[6],h=m[7],i=m[8];
    double A = e*i - f*h;
    double Bv = -(d*i - f*g);
    double Cv = d*h - e*g;
    double det = a*A + b*Bv + c*Cv;
    double r = 1.0/det;
    o[0]=A*r;  o[1]=-(b*i-c*h)*r; o[2]=(b*f-c*e)*r;
    o[3]=Bv*r; o[4]=(a*i-c*g)*r;  o[5]=-(a*f-c*d)*r;
    o[6]=Cv*r; o[7]=-(a*h-b*g)*r; o[8]=(a*e-b*d)*r;
}

// fast zero-fill: grid-stride float4
__global__ __launch_bounds__(256)
void lss_zero(float4* __restrict__ p, int n4)
{
    const int stride = gridDim.x * 256;
    for (int i = blockIdx.x * 256 + threadIdx.x; i < n4; i += stride)
        p[i] = make_float4(0.f, 0.f, 0.f, 0.f);
}

// One block (512 thr, 8 waves) per (b,n,w) column; wave wv handles h=2wv,2wv+1.
// Dedup voxels in an LDS hash table, then ONE 64-lane contiguous atomic set
// per unique voxel into ws[vox][64c] (4 cache lines per wave-atomic).
__global__ __launch_bounds__(512)
void lss_scatter_dedup(const float* __restrict__ xf,
                       const float* __restrict__ rots,
                       const float* __restrict__ trans,
                       const float* __restrict__ intr,
                       const float* __restrict__ prots,
                       const float* __restrict__ ptrans,
                       float* __restrict__ ws)
{
    __shared__ float s_lg[FHh * FWw];        // logits [h][d] (row stride 44)
    __shared__ float s_feat[FHh * CC];       // feats  [h][c]
    __shared__ float s_coef[NSLOT * 17];     // per-slot per-h coefficient (pad 17)
    __shared__ int   s_keys[NSLOT];
    __shared__ short s_list[NSLOT];          // compacted occupied-slot list
    __shared__ int   s_nslot;
    __shared__ int2  s_ovf[NOVF];
    __shared__ float s_ovfw[NOVF];
    __shared__ int   s_ovfcnt;

    const int tid  = threadIdx.x;
    const int lane = tid & 63;
    const int wv   = tid >> 6;          // 0..7

    // XCD swizzle: 1056 = 8*132; blocks on one XCD cover contiguous columns
    const int obid = blockIdx.x;
    const int bid  = (obid & 7) * (NCOL / 8) + (obid >> 3);
    const int w   = bid % FWw;
    const int rem = bid / FWw;
    const int n   = rem % NN;
    const int b   = rem / NN;
    const int cam = b*NN + n;
    const float* colbase = xf + (size_t)cam * (DD+CC) * FHh * FWw + w;

    // ---- init LDS ----
    if (tid < NSLOT) s_keys[tid] = -1;
    for (int i = tid; i < NSLOT*17; i += 512) s_coef[i] = 0.0f;
    if (tid == 0) { s_nslot = 0; s_ovfcnt = 0; }

    // ---- cooperative stage of the whole column: 1680 scalars ----
    for (int t = tid; t < (DD+CC)*FHh; t += 512) {
        int h  = t / (DD+CC);
        int ch = t - h*(DD+CC);
        float v = colbase[(size_t)ch * (FHh*FWw) + h * FWw];
        if (ch < DD) s_lg[h*FWw + ch] = v;
        else         s_feat[(h << 6) + (ch - DD)] = v;
    }

    // ---- per-camera transform (double precision, redundant per thread) ----
    double K9[9], P9[9], R9[9];
    #pragma unroll
    for (int i = 0; i < 9; ++i) {
        K9[i] = (double)intr [cam*9 + i];
        P9[i] = (double)prots[cam*9 + i];
        R9[i] = (double)rots [cam*9 + i];
    }
    double Kinv[9], Pinv[9];
    inv3x3d(K9, Kinv);
    inv3x3d(P9, Pinv);
    double M[9];
    #pragma unroll
    for (int i = 0; i < 3; ++i)
        #pragma unroll
        for (int j = 0; j < 3; ++j)
            M[i*3+j] = R9[i*3+0]*Kinv[0*3+j] + R9[i*3+1]*Kinv[1*3+j] + R9[i*3+2]*Kinv[2*3+j];
    const double tx  = (double)trans [cam*3+0], ty  = (double)trans [cam*3+1], tz  = (double)trans [cam*3+2];
    const double ptx = (double)ptrans[cam*3+0], pty = (double)ptrans[cam*3+1], ptz = (double)ptrans[cam*3+2];

    __syncthreads();

    // ---- softmax + geometry + hash insert; wave wv handles h = 2wv, 2wv+1
    for (int r = 0; r < 2; ++r) {
        const int h = (wv << 1) + r;
        float logit = (lane < DD) ? s_lg[h*FWw + lane] : -INFINITY;
        float mx = logit;
        #pragma unroll
        for (int off = 32; off; off >>= 1) mx = fmaxf(mx, __shfl_xor(mx, off));
        float ex = (lane < DD) ? expf(logit - mx) : 0.0f;
        float sm = ex;
        #pragma unroll
        for (int off = 32; off; off >>= 1) sm += __shfl_xor(sm, off);
        const float wgt = ex / sm;

        int vox = -1;
        if (lane < DD) {
            double dz = 4.0 + (double)lane;
            double xs = (double)w * (703.0/43.0);
            double ys = (double)h * 17.0;
            double px = xs - ptx, py = ys - pty, pz = dz - ptz;
            double qx = Pinv[0]*px + Pinv[1]*py + Pinv[2]*pz;
            double qy = Pinv[3]*px + Pinv[4]*py + Pinv[5]*pz;
            double qz = Pinv[6]*px + Pinv[7]*py + Pinv[8]*pz;
            qx *= qz; qy *= qz;
            double gx = M[0]*qx + M[1]*qy + M[2]*qz + tx;
            double gy = M[3]*qx + M[4]*qy + M[5]*qz + ty;
            double gz = M[6]*qx + M[7]*qy + M[8]*qz + tz;
            double fx = floor((gx + 50.0) / 0.5);
            double fy = floor((gy + 50.0) / 0.5);
            double fz = floor((gz + 10.0) / 20.0);
            if (fx >= 0.0 && fx < (double)NXg &&
                fy >= 0.0 && fy < (double)NYg &&
                fz >= 0.0 && fz < (double)NZg) {
                int ix = (int)fx, iy = (int)fy, iz = (int)fz;
                vox = ((b*NZg + iz)*NXg + ix)*NYg + iy;   // < 160000
            }
        }

        if (vox >= 0) {
            unsigned slot = (((unsigned)vox * 2654435761u) >> 18) & (NSLOT-1);
            bool done = false;
            for (int probe = 0; probe < NSLOT; ++probe) {
                int prev = atomicCAS(&s_keys[slot], -1, vox);
                if (prev == -1) {
                    int k = atomicAdd(&s_nslot, 1);
                    s_list[k] = (short)slot;
                }
                if (prev == -1 || prev == vox) {
                    atomicAdd(&s_coef[slot*17 + h], wgt);
                    done = true;
                    break;
                }
                slot = (slot + 1) & (NSLOT-1);
            }
            if (!done) {   // table full: spill (generic-correctness fallback)
                int k = atomicAdd(&s_ovfcnt, 1);
                s_ovf[k]  = make_int2(vox, h);
                s_ovfw[k] = wgt;
            }
        }
    }

    __syncthreads();

    // ---- emit: one 64-lane contiguous atomic set per unique voxel ----
    const int nocc = s_nslot;
    for (int e = wv; e < nocc; e += 8) {
        int slot = s_list[e];
        int vox  = s_keys[slot];
        float acc = 0.0f;
        #pragma unroll
        for (int h = 0; h < FHh; ++h)
            acc += s_coef[slot*17 + h] * s_feat[(h << 6) + lane];
        atomicAdd(&ws[(size_t)vox * CC + lane], acc);
    }
    // ---- overflow entries (rare, generic fallback) ----
    const int novf = s_ovfcnt;
    for (int e = wv; e < novf; e += 8) {
        int vox = s_ovf[e].x, h = s_ovf[e].y;
        atomicAdd(&ws[(size_t)vox * CC + lane], s_ovfw[e] * s_feat[(h << 6) + lane]);
    }
}

// ws [B*NZ][40000 xy][64 c]  ->  out [B*NZ][64 c][40000 xy], float4 both ways
__global__ __launch_bounds__(256)
void lss_transpose4(const float* __restrict__ ws, float* __restrict__ out)
{
    __shared__ float tile[CC][65];          // [c][xy], pad to 65
    const int blk = blockIdx.x;             // B*NZ*625 blocks
    const int bz  = blk / 625;
    const int xy0 = (blk % 625) * 64;
    const int t   = threadIdx.x;

    const float4* src = (const float4*)(ws + ((size_t)bz * XYg + xy0) * CC);
    const int xyl = t & 63;                 // load: thread owns one xy row
    #pragma unroll
    for (int rep = 0; rep < 4; ++rep) {
        int c4 = (t >> 6) + (rep << 2);     // 0..15
        float4 v = src[xyl * 16 + c4];
        tile[(c4<<2)+0][xyl] = v.x;
        tile[(c4<<2)+1][xyl] = v.y;
        tile[(c4<<2)+2][xyl] = v.z;
        tile[(c4<<2)+3][xyl] = v.w;
    }
    __syncthreads();
    float* dst = out + (size_t)bz * CC * XYg + xy0;
    const int xy4 = t & 15;                 // store: thread writes 4 xy of one c
    #pragma unroll
    for (int rep = 0; rep < 4; ++rep) {
        int c = (t >> 4) + (rep << 4);      // 0..63
        float4 v = make_float4(tile[c][(xy4<<2)+0], tile[c][(xy4<<2)+1],
                               tile[c][(xy4<<2)+2], tile[c][(xy4<<2)+3]);
        ((float4*)(dst + (size_t)c * XYg))[xy4] = v;
    }
}

extern "C" void kernel_launch(void* const* d_in, const int* in_sizes, int n_in,
                              void* d_out, int out_size, void* d_ws, size_t ws_size,
                              hipStream_t stream) {
    const float* xf     = (const float*)d_in[0];
    const float* rots   = (const float*)d_in[1];
    const float* trans  = (const float*)d_in[2];
    const float* intr   = (const float*)d_in[3];
    const float* prots  = (const float*)d_in[4];
    const float* ptrans = (const float*)d_in[5];
    float* out = (float*)d_out;

    float* ws = (float*)d_ws;   // 40.96 MB needed; d_ws is 256 MB
    lss_zero<<<dim3(2048), dim3(256), 0, stream>>>((float4*)ws, WSFLOATS/4);
    lss_scatter_dedup<<<dim3(NCOL), dim3(512), 0, stream>>>(
        xf, rots, trans, intr, prots, ptrans, ws);
    lss_transpose4<<<dim3(BB*NZg*625), dim3(256), 0, stream>>>(ws, out);
}

// Round 8
// 52.989 us; speedup vs baseline: 3.4475x; 1.0719x over previous
//
#include <hip/hip_runtime.h>
#include <math.h>

#define BB 4
#define NN 6
#define DD 41
#define CC 64
#define FHh 16
#define FWw 44
#define NXg 200
#define NYg 200
#define NZg 1
#define NSLOT 128
#define NOVF  (FHh*DD)                 // 656 worst-case points per column
#define WSFLOATS (BB*NZg*NXg*NYg*CC)   // 10,240,000 floats = 40.96 MB
#define XYg (NXg*NYg)                  // 40000
#define NCOL (BB*NN*FWw)               // 1056 columns

__device__ __forceinline__ void inv3x3d(const double m[9], double o[9]) {
    double a=m[0],b=m[1],c=m[2],d=m[3],e=m[4],f=m[5],g=m[6],h=m[7],i=m[8];
    double A = e*i - f*h;
    double Bv = -(d*i - f*g);
    double Cv = d*h - e*g;
    double det = a*A + b*Bv + c*Cv;
    double r = 1.0/det;
    o[0]=A*r;  o[1]=-(b*i-c*h)*r; o[2]=(b*f-c*e)*r;
    o[3]=Bv*r; o[4]=(a*i-c*g)*r;  o[5]=-(a*f-c*d)*r;
    o[6]=Cv*r; o[7]=-(a*h-b*g)*r; o[8]=(a*e-b*d)*r;
}

// fast zero-fill: grid-stride float4
__global__ __launch_bounds__(256)
void lss_zero(float4* __restrict__ p, int n4)
{
    const int stride = gridDim.x * 256;
    for (int i = blockIdx.x * 256 + threadIdx.x; i < n4; i += stride)
        p[i] = make_float4(0.f, 0.f, 0.f, 0.f);
}

// One block (256 thr, 4 waves) per (b,n,w) column; wave wv handles h=4wv..4wv+3.
// Dedup voxels in an LDS hash table (per-lane slot cache skips repeat probes),
// then ONE 64-lane contiguous atomic set per unique voxel into ws[vox][64c].
__global__ __launch_bounds__(256)
void lss_scatter_dedup(const float* __restrict__ xf,
                       const float* __restrict__ rots,
                       const float* __restrict__ trans,
                       const float* __restrict__ intr,
                       const float* __restrict__ prots,
                       const float* __restrict__ ptrans,
                       float* __restrict__ ws)
{
    __shared__ float s_lg[FHh * FWw];        // logits [h][d] (row stride 44)
    __shared__ float s_feat[FHh * CC];       // feats  [h][c]
    __shared__ float s_coef[NSLOT * 17];     // per-slot per-h coefficient (pad 17)
    __shared__ int   s_keys[NSLOT];
    __shared__ short s_list[NSLOT];          // compacted occupied-slot list
    __shared__ int   s_nslot;
    __shared__ int2  s_ovf[NOVF];
    __shared__ float s_ovfw[NOVF];
    __shared__ int   s_ovfcnt;

    const int tid  = threadIdx.x;
    const int lane = tid & 63;
    const int wv   = tid >> 6;          // 0..3

    // XCD swizzle: 1056 = 8*132; each XCD gets a contiguous run of columns
    const int obid = blockIdx.x;
    const int bid  = (obid & 7) * (NCOL / 8) + (obid >> 3);
    const int w   = bid % FWw;
    const int rem = bid / FWw;
    const int n   = rem % NN;
    const int b   = rem / NN;
    const int cam = b*NN + n;
    const float* colbase = xf + (size_t)cam * (DD+CC) * FHh * FWw + w;

    // ---- init LDS ----
    if (tid < NSLOT) s_keys[tid] = -1;
    for (int i = tid; i < NSLOT*17; i += 256) s_coef[i] = 0.0f;
    if (tid == 0) { s_nslot = 0; s_ovfcnt = 0; }

    // ---- cooperative stage of the whole column: 1680 scalars ----
    for (int t = tid; t < (DD+CC)*FHh; t += 256) {
        int h  = t / (DD+CC);
        int ch = t - h*(DD+CC);
        float v = colbase[(size_t)ch * (FHh*FWw) + h * FWw];
        if (ch < DD) s_lg[h*FWw + ch] = v;
        else         s_feat[(h << 6) + (ch - DD)] = v;
    }

    // ---- per-camera transform (double precision, redundant per thread) ----
    double K9[9], P9[9], R9[9];
    #pragma unroll
    for (int i = 0; i < 9; ++i) {
        K9[i] = (double)intr [cam*9 + i];
        P9[i] = (double)prots[cam*9 + i];
        R9[i] = (double)rots [cam*9 + i];
    }
    double Kinv[9], Pinv[9];
    inv3x3d(K9, Kinv);
    inv3x3d(P9, Pinv);
    double M[9];
    #pragma unroll
    for (int i = 0; i < 3; ++i)
        #pragma unroll
        for (int j = 0; j < 3; ++j)
            M[i*3+j] = R9[i*3+0]*Kinv[0*3+j] + R9[i*3+1]*Kinv[1*3+j] + R9[i*3+2]*Kinv[2*3+j];
    const double tx  = (double)trans [cam*3+0], ty  = (double)trans [cam*3+1], tz  = (double)trans [cam*3+2];
    const double ptx = (double)ptrans[cam*3+0], pty = (double)ptrans[cam*3+1], ptz = (double)ptrans[cam*3+2];

    __syncthreads();

    // ---- softmax + geometry + hash insert; wave wv handles h = 4wv..4wv+3
    int      last_vox  = -1;     // per-lane (vox -> slot) cache across h
    unsigned last_slot = 0;
    for (int r = 0; r < 4; ++r) {
        const int h = (wv << 2) + r;
        float logit = (lane < DD) ? s_lg[h*FWw + lane] : -INFINITY;
        float mx = logit;
        #pragma unroll
        for (int off = 32; off; off >>= 1) mx = fmaxf(mx, __shfl_xor(mx, off));
        float ex = (lane < DD) ? expf(logit - mx) : 0.0f;
        float sm = ex;
        #pragma unroll
        for (int off = 32; off; off >>= 1) sm += __shfl_xor(sm, off);
        const float wgt = ex / sm;

        int vox = -1;
        if (lane < DD) {
            double dz = 4.0 + (double)lane;
            double xs = (double)w * (703.0/43.0);
            double ys = (double)h * 17.0;
            double px = xs - ptx, py = ys - pty, pz = dz - ptz;
            double qx = Pinv[0]*px + Pinv[1]*py + Pinv[2]*pz;
            double qy = Pinv[3]*px + Pinv[4]*py + Pinv[5]*pz;
            double qz = Pinv[6]*px + Pinv[7]*py + Pinv[8]*pz;
            qx *= qz; qy *= qz;
            double gx = M[0]*qx + M[1]*qy + M[2]*qz + tx;
            double gy = M[3]*qx + M[4]*qy + M[5]*qz + ty;
            double gz = M[6]*qx + M[7]*qy + M[8]*qz + tz;
            double fx = floor((gx + 50.0) / 0.5);
            double fy = floor((gy + 50.0) / 0.5);
            double fz = floor((gz + 10.0) / 20.0);
            if (fx >= 0.0 && fx < (double)NXg &&
                fy >= 0.0 && fy < (double)NYg &&
                fz >= 0.0 && fz < (double)NZg) {
                int ix = (int)fx, iy = (int)fy, iz = (int)fz;
                vox = ((b*NZg + iz)*NXg + ix)*NYg + iy;   // < 160000
            }
        }

        if (vox >= 0) {
            if (vox == last_vox) {
                // same voxel as previous h for this lane: slot already known
                atomicAdd(&s_coef[last_slot*17 + h], wgt);
            } else {
                unsigned slot = (((unsigned)vox * 2654435761u) >> 18) & (NSLOT-1);
                bool done = false;
                for (int probe = 0; probe < NSLOT; ++probe) {
                    int prev = atomicCAS(&s_keys[slot], -1, vox);
                    if (prev == -1) {
                        int k = atomicAdd(&s_nslot, 1);
                        s_list[k] = (short)slot;
                    }
                    if (prev == -1 || prev == vox) {
                        atomicAdd(&s_coef[slot*17 + h], wgt);
                        last_vox = vox; last_slot = slot;
                        done = true;
                        break;
                    }
                    slot = (slot + 1) & (NSLOT-1);
                }
                if (!done) {   // table full: spill (generic-correctness fallback)
                    int k = atomicAdd(&s_ovfcnt, 1);
                    s_ovf[k]  = make_int2(vox, h);
                    s_ovfw[k] = wgt;
                    last_vox = -1;
                }
            }
        }
    }

    __syncthreads();

    // ---- emit: one 64-lane contiguous atomic set per unique voxel ----
    const int nocc = s_nslot;
    for (int e = wv; e < nocc; e += 4) {
        int slot = s_list[e];
        int vox  = s_keys[slot];
        float acc = 0.0f;
        #pragma unroll
        for (int h = 0; h < FHh; ++h)
            acc += s_coef[slot*17 + h] * s_feat[(h << 6) + lane];
        atomicAdd(&ws[(size_t)vox * CC + lane], acc);
    }
    // ---- overflow entries (rare, generic fallback) ----
    const int novf = s_ovfcnt;
    for (int e = wv; e < novf; e += 4) {
        int vox = s_ovf[e].x, h = s_ovf[e].y;
        atomicAdd(&ws[(size_t)vox * CC + lane], s_ovfw[e] * s_feat[(h << 6) + lane]);
    }
}

// ws [bz][40000 xy][64 c] -> out [bz][64 c][40000 xy]
// Reads: each wave-instr loads 1 KB CONTIGUOUS (64 consecutive float4).
// Writes: 4×256 B contiguous segments per wave-instr.
__global__ __launch_bounds__(256)
void lss_transpose_c(const float* __restrict__ ws, float* __restrict__ out)
{
    __shared__ float tile[CC][65];          // [c][xy], pad 65
    const int blk  = blockIdx.x;            // 4*625 = 2500 blocks
    const int bz   = blk / 625;
    const int xy0  = (blk % 625) * 64;
    const int t    = threadIdx.x;
    const int lane = t & 63;
    const int wv   = t >> 6;                // 0..3

    const float4* src = (const float4*)(ws + ((size_t)bz * XYg + xy0) * CC);
    #pragma unroll
    for (int rep = 0; rep < 4; ++rep) {
        int idx = (wv << 8) + (rep << 6) + lane;   // 64 consecutive float4/wave
        int xyl = idx >> 4;                        // 0..63
        int c4  = idx & 15;                        // float4 group within c
        float4 v = src[idx];
        tile[(c4<<2)+0][xyl] = v.x;
        tile[(c4<<2)+1][xyl] = v.y;
        tile[(c4<<2)+2][xyl] = v.z;
        tile[(c4<<2)+3][xyl] = v.w;
    }
    __syncthreads();
    float* dst = out + (size_t)bz * CC * XYg + xy0;
    #pragma unroll
    for (int rep = 0; rep < 4; ++rep) {
        int c   = (wv << 4) + (rep << 2) + (lane >> 4);  // 0..63
        int xy4 = lane & 15;                             // float4 within row
        float4 v = make_float4(tile[c][(xy4<<2)+0], tile[c][(xy4<<2)+1],
                               tile[c][(xy4<<2)+2], tile[c][(xy4<<2)+3]);
        ((float4*)(dst + (size_t)c * XYg))[xy4] = v;
    }
}

extern "C" void kernel_launch(void* const* d_in, const int* in_sizes, int n_in,
                              void* d_out, int out_size, void* d_ws, size_t ws_size,
                              hipStream_t stream) {
    const float* xf     = (const float*)d_in[0];
    const float* rots   = (const float*)d_in[1];
    const float* trans  = (const float*)d_in[2];
    const float* intr   = (const float*)d_in[3];
    const float* prots  = (const float*)d_in[4];
    const float* ptrans = (const float*)d_in[5];
    float* out = (float*)d_out;

    float* ws = (float*)d_ws;   // 40.96 MB needed; d_ws is larger
    lss_zero<<<dim3(2048), dim3(256), 0, stream>>>((float4*)ws, WSFLOATS/4);
    lss_scatter_dedup<<<dim3(NCOL), dim3(256), 0, stream>>>(
        xf, rots, trans, intr, prots, ptrans, ws);
    lss_transpose_c<<<dim3(BB*NZg*625), dim3(256), 0, stream>>>(ws, out);
}